// Round 1
// baseline (771.838 us; speedup 1.0000x reference)
//
#include <hip/hip_runtime.h>
#include <hip/hip_bf16.h>

#define KM1   1023
#define NROWS (1024 * 1023)          // 1047552 off-diagonal pairs
#define TILE  32                     // pairs per tile
#define TPB   8                      // tiles per block
#define THREADS 256
#define NBLOCK (NROWS / (TILE * TPB))   // 4092 exactly

typedef __attribute__((ext_vector_type(8))) short bf16x8;   // 8 bf16 (4 VGPRs) — MFMA A/B frag
typedef __attribute__((ext_vector_type(4))) float floatx4;  // MFMA C/D frag

__device__ __forceinline__ unsigned short f2bf(float f) {
    return __builtin_bit_cast(unsigned short, __float2bfloat16(f));
}
__device__ __forceinline__ float bf2f(unsigned short u) {
    return __builtin_bit_cast(float, (unsigned)u << 16);
}

// One-time repack into workspace (49152 B):
//   ws[0     ..16383] : w2t  [n][k]  bf16  (W2 transposed)      -> L2 MFMA A-side
//   ws[16384 ..20479] : w1thi[c][32] bf16  (W1 transposed, hi)  -> L1 MFMA A-side
//   ws[20480 ..24575] : w1tlo[c][32] bf16  (W1 transposed, lo)
__global__ void prep(const float* __restrict__ W1, const float* __restrict__ W2,
                     unsigned short* __restrict__ ws) {
    int idx = blockIdx.x * 256 + threadIdx.x;   // 80*256 = 20480 exactly
    if (idx < 16384) {
        int n = idx >> 7, k = idx & 127;
        ws[n * 128 + k] = f2bf(W2[k * 128 + n]);
    } else {
        int j = idx - 16384;                    // 0..4095
        int c = j >> 5, k = j & 31;             // k padded 13 -> 32 with zeros
        float v = (k < 13) ? W1[k * 128 + c] : 0.0f;
        unsigned short hi = f2bf(v);
        ws[16384 + c * 32 + k] = hi;
        ws[20480 + c * 32 + k] = f2bf(v - bf2f(hi));
    }
}

__global__ __launch_bounds__(THREADS, 4)
void pair_mlp(const float* __restrict__ boxes,
              const float* __restrict__ b1,
              const float* __restrict__ b2,
              const unsigned short* __restrict__ wsro,
              float* __restrict__ out) {
    // Only h lives in LDS: [buf][hi/lo][32 pairs][128 k] bf16, XOR-swizzled, 32768 B total.
    __shared__ __align__(16) unsigned short sH[2][2][32 * 128];

    const unsigned short* w2t   = wsro;
    const unsigned short* w1thi = wsro + 16384;
    const unsigned short* w1tlo = wsro + 20480;

    const int tid   = threadIdx.x;
    const int lane  = tid & 63;
    const int wave  = tid >> 6;          // 4 waves
    const int phalf = wave & 1;          // pair half (0..1)
    const int nh    = wave >> 1;         // L2: 64-col half; L1: 64-c half (wave-specialized)
    const int lr    = lane & 15;
    const int q     = lane >> 4;
    const int p     = phalf * 16 + lr;   // this lane's local pair (0..31)
    const int swz   = lr << 4;           // row-keyed XOR swizzle ((p&15)<<4): conflict-free b128 reads
    const int rowb  = p << 8;            // p * 256 B (128 bf16 per row)
    const unsigned pbase = blockIdx.x * (TILE * TPB);

    for (int t = 0; t < TPB; ++t) {
        char* hbase = (char*)&sH[t & 1][0][0];
        char* lbase = hbase + 8192;

        // ---- features entirely in registers (one pair per lane, no LDS round-trip) ----
        const unsigned r = pbase + t * TILE + p;
        unsigned bi_ = r / KM1;                       // magic-mul const division
        unsigned rem = r - bi_ * KM1;
        unsigned bj_ = rem + (rem >= bi_ ? 1u : 0u);
        float4 bA = *(const float4*)(boxes + 4u * bi_);
        float4 bB = *(const float4*)(boxes + 4u * bj_);
        float xi = bA.x, yi = bA.y, wi = bA.z, hi = bA.w;
        float xj = bB.x, yj = bB.y, wj = bB.z, hj = bB.w;
        float dx = (xj - xi) / wi;
        float dy = (yj - yi) / hi;
        float dw = __logf(wj / wi + 1e-6f);
        float dh = __logf(hj / hi + 1e-6f);
        float iw = fmaxf(0.0f, fminf(xi + wi, xj + wj) - fmaxf(xi, xj));
        float ih = fmaxf(0.0f, fminf(yi + hi, yj + hj) - fmaxf(yi, yj));
        float inter = iw * ih;
        float uni   = wi * hi + wj * hj - inter;
        float iou   = inter / (uni + 1e-6f);

        // B1-frag: lane holds F[p][k = q*8+e] (k >= 13 zero-padded), split hi/lo
        float fA[8] = {dx, dy, dw, dh, wi, hi, wj, hj};
        float fB[8] = {iou, xi, yi, xj, yj, 0.f, 0.f, 0.f};
        bf16x8 Fhi, Flo;
        #pragma unroll
        for (int e = 0; e < 8; ++e) {
            float v = (q == 0) ? fA[e] : ((q == 1) ? fB[e] : 0.0f);
            unsigned short vh = f2bf(v);
            Fhi[e] = (short)vh;
            Flo[e] = (short)f2bf(v - bf2f(vh));
        }

        // ---- layer 1: C1[c][p] = W1^T * F^T + b1, wave-specialized (this wave: c in nh-half) ----
        // 3-term split: Whi*Fhi + Whi*Flo + Wlo*Fhi  (dropped Wlo*Flo ~ 2^-18 rel)
        {
            bf16x8 whi[4], wlo[4];
            floatx4 a1[4];
            #pragma unroll
            for (int m = 0; m < 4; ++m) {
                const int mt = nh * 4 + m;          // c-tile
                const int c  = mt * 16 + lr;        // A-frag row -> c
                whi[m] = *(const bf16x8*)(w1thi + c * 32 + q * 8);
                wlo[m] = *(const bf16x8*)(w1tlo + c * 32 + q * 8);
                a1[m]  = *(const floatx4*)(b1 + mt * 16 + q * 4);   // bias folded into C-init
            }
            #pragma unroll
            for (int m = 0; m < 4; ++m) {
                a1[m] = __builtin_amdgcn_mfma_f32_16x16x32_bf16(whi[m], Fhi, a1[m], 0, 0, 0);
                a1[m] = __builtin_amdgcn_mfma_f32_16x16x32_bf16(whi[m], Flo, a1[m], 0, 0, 0);
                a1[m] = __builtin_amdgcn_mfma_f32_16x16x32_bf16(wlo[m], Fhi, a1[m], 0, 0, 0);
            }
            // relu + hi/lo split + packed b64 LDS writes (C1: lane holds h[c=mt*16+q*4+e][own p])
            #pragma unroll
            for (int m = 0; m < 4; ++m) {
                const int mt = nh * 4 + m;
                unsigned short hh[4], hl[4];
                #pragma unroll
                for (int e = 0; e < 4; ++e) {
                    float h = fmaxf(a1[m][e], 0.0f);
                    hh[e] = f2bf(h);
                    hl[e] = f2bf(h - bf2f(hh[e]));
                }
                const int kb = (mt * 32 + q * 8) ^ swz;
                uint2 uh, ul;
                uh.x = (unsigned)hh[0] | ((unsigned)hh[1] << 16);
                uh.y = (unsigned)hh[2] | ((unsigned)hh[3] << 16);
                ul.x = (unsigned)hl[0] | ((unsigned)hl[1] << 16);
                ul.y = (unsigned)hl[2] | ((unsigned)hl[3] << 16);
                *(uint2*)(hbase + rowb + kb) = uh;
                *(uint2*)(lbase + rowb + kb) = ul;
            }
        }

        __syncthreads();   // single barrier per tile (double-buffered sH)

        // ---- layer 2: C2[n][p] = W2^T * h^T + b2 ; W2 frags straight from L1/L2 cache ----
        floatx4 a2[4];
        #pragma unroll
        for (int nt = 0; nt < 4; ++nt)
            a2[nt] = *(const floatx4*)(b2 + nh * 64 + nt * 16 + q * 4);  // bias in C-init
        #pragma unroll
        for (int ks = 0; ks < 4; ++ks) {
            const int kb = (ks * 64 + q * 16) ^ swz;
            bf16x8 Bhi = *(const bf16x8*)(hbase + rowb + kb);   // h[p][k=ks*32+q*8 ..+7] hi
            bf16x8 Blo = *(const bf16x8*)(lbase + rowb + kb);
            #pragma unroll
            for (int nt = 0; nt < 4; ++nt) {
                const int n = nh * 64 + nt * 16 + lr;
                bf16x8 A2 = *(const bf16x8*)(w2t + n * 128 + ks * 32 + q * 8);
                a2[nt] = __builtin_amdgcn_mfma_f32_16x16x32_bf16(A2, Bhi, a2[nt], 0, 0, 0);
                a2[nt] = __builtin_amdgcn_mfma_f32_16x16x32_bf16(A2, Blo, a2[nt], 0, 0, 0);
            }
        }

        // ---- epilogue: C2 rows are consecutive out columns -> float4 stores ----
        float* orow = out + (size_t)(pbase + t * TILE + p) * 128 + nh * 64 + q * 4;
        #pragma unroll
        for (int nt = 0; nt < 4; ++nt)
            *(floatx4*)(orow + nt * 16) = a2[nt];
    }
}

extern "C" void kernel_launch(void* const* d_in, const int* in_sizes, int n_in,
                              void* d_out, int out_size, void* d_ws, size_t ws_size,
                              hipStream_t stream) {
    (void)in_sizes; (void)n_in; (void)out_size; (void)ws_size;
    const float* boxes = (const float*)d_in[0];
    const float* W1    = (const float*)d_in[1];
    const float* b1    = (const float*)d_in[2];
    const float* W2    = (const float*)d_in[3];
    const float* b2    = (const float*)d_in[4];
    float* out = (float*)d_out;
    unsigned short* ws = (unsigned short*)d_ws;   // 48 KB scratch

    prep<<<80, THREADS, 0, stream>>>(W1, W2, ws);
    pair_mlp<<<NBLOCK, THREADS, 0, stream>>>(boxes, b1, b2, ws, out);
}